// Round 1
// baseline (451.191 us; speedup 1.0000x reference)
//
#include <hip/hip_runtime.h>
#include <hip/hip_bf16.h>
#include <math.h>

#define Bn 16
#define Cc 256
#define Oo 128
#define HWn 4096
#define Ntot 65536   // Bn*HWn
#define KC 64
#define HWT 128

// ---------------- conv1x1 GEMM + per-channel stats ----------------
// out[b,o,hw] = sum_c w[o,c]*in[b,c,hw] + bias[o]; atomically accumulate
// per-o sum and sumsq over all (b,hw).
__global__ __launch_bounds__(256, 2)
void conv_bn_stats(const float* __restrict__ in, const float* __restrict__ w,
                   const float* __restrict__ bias, float* __restrict__ out,
                   float* __restrict__ osum, float* __restrict__ osq)
{
    __shared__ float in_s[KC][HWT + 8];   // stride 136 floats (16B aligned)
    __shared__ float w_s[Oo][KC + 1];     // stride 65 (scalar reads, conflict-free)

    const int t   = threadIdx.x;
    const int b   = blockIdx.y;
    const int hw0 = blockIdx.x * HWT;
    const int to  = t >> 4;   // 0..15 -> o block of 8
    const int thw = t & 15;   // 0..15 -> hw cols thw*4..+3 and 64+thw*4..+3

    const int c4 = t & 31, r0 = t >> 5;    // input staging
    const int wto = t >> 4, wc4 = t & 15;  // weight staging

    float acc[8][8];
#pragma unroll
    for (int i = 0; i < 8; i++)
#pragma unroll
        for (int j = 0; j < 8; j++) acc[i][j] = 0.f;

    for (int kc = 0; kc < Cc; kc += KC) {
        // stage input chunk [KC][HWT]
#pragma unroll
        for (int rr = 0; rr < 8; rr++) {
            int r = rr * 8 + r0;
            const float4 v = *(const float4*)(in + (size_t)(b * Cc + kc + r) * HWn + hw0 + c4 * 4);
            *(float4*)&in_s[r][c4 * 4] = v;
        }
        // stage weight chunk [Oo][KC]
#pragma unroll
        for (int i = 0; i < 8; i++) {
            int o = i * 16 + wto;
            const float4 v = *(const float4*)(w + (size_t)o * Cc + kc + wc4 * 4);
            w_s[o][wc4 * 4 + 0] = v.x;
            w_s[o][wc4 * 4 + 1] = v.y;
            w_s[o][wc4 * 4 + 2] = v.z;
            w_s[o][wc4 * 4 + 3] = v.w;
        }
        __syncthreads();

#pragma unroll 8
        for (int k = 0; k < KC; k++) {
            const float4 a0 = *(const float4*)&in_s[k][thw * 4];
            const float4 a1 = *(const float4*)&in_s[k][64 + thw * 4];
            float wv[8];
#pragma unroll
            for (int i = 0; i < 8; i++) wv[i] = w_s[to * 8 + i][k];
#pragma unroll
            for (int i = 0; i < 8; i++) {
                acc[i][0] += wv[i] * a0.x; acc[i][1] += wv[i] * a0.y;
                acc[i][2] += wv[i] * a0.z; acc[i][3] += wv[i] * a0.w;
                acc[i][4] += wv[i] * a1.x; acc[i][5] += wv[i] * a1.y;
                acc[i][6] += wv[i] * a1.z; acc[i][7] += wv[i] * a1.w;
            }
        }
        __syncthreads();
    }

    // epilogue: bias, store, per-channel stats
#pragma unroll
    for (int i = 0; i < 8; i++) {
        const int o = to * 8 + i;
        const float bo = bias[o];
        float4 v0, v1;
        v0.x = acc[i][0] + bo; v0.y = acc[i][1] + bo; v0.z = acc[i][2] + bo; v0.w = acc[i][3] + bo;
        v1.x = acc[i][4] + bo; v1.y = acc[i][5] + bo; v1.z = acc[i][6] + bo; v1.w = acc[i][7] + bo;
        float* op = out + (size_t)(b * Oo + o) * HWn + hw0;
        *(float4*)(op + thw * 4) = v0;
        *(float4*)(op + 64 + thw * 4) = v1;
        float s1 = v0.x + v0.y + v0.z + v0.w + v1.x + v1.y + v1.z + v1.w;
        float s2 = v0.x * v0.x + v0.y * v0.y + v0.z * v0.z + v0.w * v0.w
                 + v1.x * v1.x + v1.y * v1.y + v1.z * v1.z + v1.w * v1.w;
#pragma unroll
        for (int d = 1; d < 16; d <<= 1) {
            s1 += __shfl_xor(s1, d);
            s2 += __shfl_xor(s2, d);
        }
        if (thw == 0) {
            atomicAdd(&osum[o], s1);
            atomicAdd(&osq[o], s2);
        }
    }
}

// ---------------- finalize BN stats for both convs ----------------
// coef[o] = (gscale, xscale, gshift+xshift, psi_w[o])
__global__ void finalize1(const float* __restrict__ gsum, const float* __restrict__ gsq,
                          const float* __restrict__ xsum, const float* __restrict__ xsq,
                          const float* __restrict__ wg_gamma, const float* __restrict__ wg_beta,
                          const float* __restrict__ wx_gamma, const float* __restrict__ wx_beta,
                          const float* __restrict__ psi_w, float4* __restrict__ coef)
{
    const int o = threadIdx.x;
    const float invN = 1.f / (float)Ntot;
    float mg = gsum[o] * invN;
    float vg = gsq[o] * invN - mg * mg;
    float gs = wg_gamma[o] * rsqrtf(vg + 1e-5f);
    float gh = wg_beta[o] - mg * gs;
    float mx = xsum[o] * invN;
    float vx = xsq[o] * invN - mx * mx;
    float xs = wx_gamma[o] * rsqrtf(vx + 1e-5f);
    float xh = wx_beta[o] - mx * xs;
    coef[o] = make_float4(gs, xs, gh + xh, psi_w[o]);
}

// ---------------- psi pre-activation: s[p] = psi_b + sum_o pw*relu(...) ----------------
__global__ __launch_bounds__(256)
void psi_pre_kernel(const float* __restrict__ tg, const float* __restrict__ tx,
                    const float4* __restrict__ coef, const float* __restrict__ pb,
                    float* __restrict__ S, float* __restrict__ psum)
{
    const int p = blockIdx.x * 256 + threadIdx.x;   // 0..65535
    const int b = p >> 12;
    const int hw = p & 4095;
    const float* g0 = tg + (size_t)b * Oo * HWn + hw;
    const float* x0 = tx + (size_t)b * Oo * HWn + hw;
    float s = pb[0];
#pragma unroll 8
    for (int o = 0; o < Oo; o++) {
        const float4 cf = coef[o];                 // uniform -> scalar load
        const float gv = g0[(size_t)o * HWn];
        const float xv = x0[(size_t)o * HWn];
        const float z = cf.x * gv + cf.y * xv + cf.z;
        s += cf.w * fmaxf(z, 0.f);
    }
    S[p] = s;
    float s1 = s, s2 = s * s;
#pragma unroll
    for (int d = 1; d < 64; d <<= 1) {
        s1 += __shfl_xor(s1, d);
        s2 += __shfl_xor(s2, d);
    }
    __shared__ float r1[4], r2[4];
    const int wid = threadIdx.x >> 6, lid = threadIdx.x & 63;
    if (lid == 0) { r1[wid] = s1; r2[wid] = s2; }
    __syncthreads();
    if (threadIdx.x == 0) {
        atomicAdd(&psum[0], r1[0] + r1[1] + r1[2] + r1[3]);
        atomicAdd(&psum[1], r2[0] + r2[1] + r2[2] + r2[3]);
    }
}

__global__ void finalize2(const float* __restrict__ psum, const float* __restrict__ psi_gamma,
                          const float* __restrict__ psi_beta, float* __restrict__ pc)
{
    const float invN = 1.f / (float)Ntot;
    const float m = psum[0] * invN;
    const float v = psum[1] * invN - m * m;
    const float ps = psi_gamma[0] * rsqrtf(v + 1e-5f);
    pc[0] = ps;
    pc[1] = psi_beta[0] - m * ps;
}

// ---------------- out = x * sigmoid(pscale*s + pshift) ----------------
__global__ __launch_bounds__(256)
void final_mul_kernel(const float* __restrict__ x, const float* __restrict__ S,
                      const float* __restrict__ pc, float* __restrict__ out)
{
    const size_t i = ((size_t)blockIdx.x * 256 + threadIdx.x) * 4;
    const int hw = (int)(i & 4095);
    const size_t bc = i >> 12;
    const int b = (int)(bc >> 8);
    const float ps = pc[0], psh = pc[1];
    const float4 xv = *(const float4*)(x + i);
    const float4 sv = *(const float4*)(S + ((size_t)b << 12) + hw);
    float4 r;
    r.x = xv.x * (1.f / (1.f + __expf(-(ps * sv.x + psh))));
    r.y = xv.y * (1.f / (1.f + __expf(-(ps * sv.y + psh))));
    r.z = xv.z * (1.f / (1.f + __expf(-(ps * sv.z + psh))));
    r.w = xv.w * (1.f / (1.f + __expf(-(ps * sv.w + psh))));
    *(float4*)(out + i) = r;
}

extern "C" void kernel_launch(void* const* d_in, const int* in_sizes, int n_in,
                              void* d_out, int out_size, void* d_ws, size_t ws_size,
                              hipStream_t stream)
{
    const float* g         = (const float*)d_in[0];
    const float* x         = (const float*)d_in[1];
    const float* wg_w      = (const float*)d_in[2];
    const float* wg_b      = (const float*)d_in[3];
    const float* wg_gamma  = (const float*)d_in[4];
    const float* wg_beta   = (const float*)d_in[5];
    const float* wx_w      = (const float*)d_in[6];
    const float* wx_b      = (const float*)d_in[7];
    const float* wx_gamma  = (const float*)d_in[8];
    const float* wx_beta   = (const float*)d_in[9];
    const float* psi_w     = (const float*)d_in[10];
    const float* psi_b     = (const float*)d_in[11];
    const float* psi_gamma = (const float*)d_in[12];
    const float* psi_beta  = (const float*)d_in[13];

    float* out = (float*)d_out;
    // d_out doubles as scratch for the two conv outputs (exactly 64 MB),
    // fully overwritten by final_mul_kernel afterwards.
    float* tg = out;
    float* tx = out + (size_t)Bn * Oo * HWn;   // +8388608

    float* ws   = (float*)d_ws;
    float* S    = ws;                 // 65536 floats
    float* gsum = ws + 65536;         // 128
    float* gsq  = ws + 65664;         // 128
    float* xsum = ws + 65792;         // 128
    float* xsq  = ws + 65920;         // 128
    float* psum = ws + 66048;         // 2 (+2 pad)
    float4* coef = (float4*)(ws + 66052);  // 128 float4
    float* pc   = ws + 66564;         // 2

    // zero the stat accumulators (65536..66052)
    hipMemsetAsync(gsum, 0, 516 * sizeof(float), stream);

    conv_bn_stats<<<dim3(HWn / HWT, Bn), 256, 0, stream>>>(g, wg_w, wg_b, tg, gsum, gsq);
    conv_bn_stats<<<dim3(HWn / HWT, Bn), 256, 0, stream>>>(x, wx_w, wx_b, tx, xsum, xsq);
    finalize1<<<1, 128, 0, stream>>>(gsum, gsq, xsum, xsq, wg_gamma, wg_beta,
                                     wx_gamma, wx_beta, psi_w, coef);
    psi_pre_kernel<<<Ntot / 256, 256, 0, stream>>>(tg, tx, coef, psi_b, S, psum);
    finalize2<<<1, 1, 0, stream>>>(psum, psi_gamma, psi_beta, pc);
    final_mul_kernel<<<(Ntot * Cc) / (4 * 256), 256, 0, stream>>>(x, S, pc, out);
}

// Round 2
// 363.401 us; speedup vs baseline: 1.2416x; 1.2416x over previous
//
#include <hip/hip_runtime.h>
#include <hip/hip_bf16.h>
#include <math.h>

#define Bn 16
#define Cc 256
#define Oo 128
#define HWn 4096
#define Ntot 65536   // Bn*HWn
#define BK 64

typedef __attribute__((ext_vector_type(8))) __bf16 bf16x8;
typedef __attribute__((ext_vector_type(8))) short short8;
typedef __attribute__((ext_vector_type(4))) float f32x4;

__device__ __forceinline__ unsigned short f2bf(float f) {
    unsigned u = __builtin_bit_cast(unsigned, f);
    u = (u + 0x7FFFu + ((u >> 16) & 1u)) >> 16;
    return (unsigned short)u;
}

// ---------------- fused conv1x1 (bf16 MFMA) + bias + per-channel stats ----------------
// z=0: tg = wg_w @ g + wg_b ; z=1: tx = wx_w @ x + wx_b
// Tile: M=128 (o) x N=128 (hw), K=256, BK=64. 4 waves in 2x2, each wave 64x64 (4x4 frags).
__global__ __launch_bounds__(256, 2)
void conv_mfma(const float* __restrict__ gin, const float* __restrict__ xin,
               const float* __restrict__ wgw, const float* __restrict__ wgb,
               const float* __restrict__ wxw, const float* __restrict__ wxb,
               float* __restrict__ tg, float* __restrict__ tx,
               float* __restrict__ gsum, float* __restrict__ gsq,
               float* __restrict__ xsum, float* __restrict__ xsq)
{
    const int z = blockIdx.z;
    const float* in   = z ? xin : gin;
    const float* w    = z ? wxw : wgw;
    const float* bias = z ? wxb : wgb;
    float* out  = z ? tx : tg;
    float* osum = z ? xsum : gsum;
    float* osq  = z ? xsq : gsq;

    __shared__ short A_s[128][72];     // [o][c] bf16, row stride 144 B (16B-aligned b128 reads)
    __shared__ unsigned int B_s[32][129]; // [c2][hw] packed (bf16 c, bf16 c+1), row 516 B

    const int t    = threadIdx.x;
    const int b    = blockIdx.y;
    const int hw0  = blockIdx.x * 128;
    const int lane = t & 63;
    const int wv   = t >> 6;
    const int m0   = (wv & 1) * 64;   // o offset in tile
    const int n0   = (wv >> 1) * 64;  // hw offset in tile
    const int q    = lane >> 4;
    const int r    = lane & 15;

    // staging indices
    const int su  = t & 31;   // B: hw block (hw = su*4)
    const int sc2 = t >> 5;   // B: c-pair row 0..7
    const int au  = t & 15;   // A: c block (c = au*4)
    const int ao  = t >> 4;   // A: o 0..15 (step 16)

    f32x4 acc[4][4];
#pragma unroll
    for (int i = 0; i < 4; i++)
#pragma unroll
        for (int j = 0; j < 4; j++) acc[i][j] = (f32x4){0.f, 0.f, 0.f, 0.f};

    for (int kc = 0; kc < Cc; kc += BK) {
        // stage A: w[o][kc..kc+63] -> A_s (bf16)
#pragma unroll
        for (int i = 0; i < 8; i++) {
            const int o = ao + i * 16;
            const float4 v = *(const float4*)(w + o * Cc + kc + au * 4);
            unsigned int lo = (unsigned)f2bf(v.x) | ((unsigned)f2bf(v.y) << 16);
            unsigned int hi = (unsigned)f2bf(v.z) | ((unsigned)f2bf(v.w) << 16);
            *(uint2*)&A_s[o][au * 4] = make_uint2(lo, hi);
        }
        // stage B: in[b][kc..kc+63][hw0..hw0+127] -> B_s (c-pair packed bf16)
#pragma unroll
        for (int i = 0; i < 4; i++) {
            const int c2 = sc2 + i * 8;
            const int c  = kc + c2 * 2;
            const float4 v0 = *(const float4*)(in + (b * Cc + c) * HWn + hw0 + su * 4);
            const float4 v1 = *(const float4*)(in + (b * Cc + c + 1) * HWn + hw0 + su * 4);
            B_s[c2][su * 4 + 0] = (unsigned)f2bf(v0.x) | ((unsigned)f2bf(v1.x) << 16);
            B_s[c2][su * 4 + 1] = (unsigned)f2bf(v0.y) | ((unsigned)f2bf(v1.y) << 16);
            B_s[c2][su * 4 + 2] = (unsigned)f2bf(v0.z) | ((unsigned)f2bf(v1.z) << 16);
            B_s[c2][su * 4 + 3] = (unsigned)f2bf(v0.w) | ((unsigned)f2bf(v1.w) << 16);
        }
        __syncthreads();

#pragma unroll
        for (int ks = 0; ks < 2; ks++) {
            bf16x8 af[4];
#pragma unroll
            for (int mi = 0; mi < 4; mi++)
                af[mi] = *(const bf16x8*)&A_s[m0 + mi * 16 + r][ks * 32 + q * 8];
#pragma unroll
            for (int ni = 0; ni < 4; ni++) {
                unsigned int bw[4];
                const int nn = n0 + ni * 16 + r;
                const int row = ks * 16 + q * 4;
#pragma unroll
                for (int jj = 0; jj < 4; jj++) bw[jj] = B_s[row + jj][nn];
                const bf16x8 bfr = *(const bf16x8*)bw;
#pragma unroll
                for (int mi = 0; mi < 4; mi++)
                    acc[mi][ni] = __builtin_amdgcn_mfma_f32_16x16x32_bf16(af[mi], bfr, acc[mi][ni], 0, 0, 0);
            }
        }
        __syncthreads();
    }

    // epilogue: bias, store fp32, per-o stats
#pragma unroll
    for (int mi = 0; mi < 4; mi++) {
#pragma unroll
        for (int reg = 0; reg < 4; reg++) {
            const int o = m0 + mi * 16 + q * 4 + reg;
            const float bo = bias[o];
            float s1 = 0.f, s2 = 0.f;
#pragma unroll
            for (int ni = 0; ni < 4; ni++) {
                const float v = acc[mi][ni][reg] + bo;
                out[((b * Oo + o) << 12) + hw0 + n0 + ni * 16 + r] = v;
                s1 += v; s2 += v * v;
            }
#pragma unroll
            for (int d = 1; d < 16; d <<= 1) {
                s1 += __shfl_xor(s1, d);
                s2 += __shfl_xor(s2, d);
            }
            if (r == 0) { atomicAdd(&osum[o], s1); atomicAdd(&osq[o], s2); }
        }
    }
}

// ---------------- finalize BN stats for both convs ----------------
__global__ void finalize1(const float* __restrict__ gsum, const float* __restrict__ gsq,
                          const float* __restrict__ xsum, const float* __restrict__ xsq,
                          const float* __restrict__ wg_gamma, const float* __restrict__ wg_beta,
                          const float* __restrict__ wx_gamma, const float* __restrict__ wx_beta,
                          const float* __restrict__ psi_w, float4* __restrict__ coef)
{
    const int o = threadIdx.x;
    const float invN = 1.f / (float)Ntot;
    float mg = gsum[o] * invN;
    float vg = gsq[o] * invN - mg * mg;
    float gs = wg_gamma[o] * rsqrtf(vg + 1e-5f);
    float gh = wg_beta[o] - mg * gs;
    float mx = xsum[o] * invN;
    float vx = xsq[o] * invN - mx * mx;
    float xs = wx_gamma[o] * rsqrtf(vx + 1e-5f);
    float xh = wx_beta[o] - mx * xs;
    coef[o] = make_float4(gs, xs, gh + xh, psi_w[o]);
}

// ---------------- psi partial: atomic-add 32-o partial into S ----------------
__global__ __launch_bounds__(256)
void psi_partial(const float* __restrict__ tg, const float* __restrict__ tx,
                 const float4* __restrict__ coef, float* __restrict__ S)
{
    const int p  = blockIdx.x * 256 + threadIdx.x;
    const int b  = p >> 12;
    const int hw = p & 4095;
    const int og = blockIdx.y * 32;
    const float* g0 = tg + ((b * Oo) << 12) + hw;
    const float* x0 = tx + ((b * Oo) << 12) + hw;
    float s = 0.f;
#pragma unroll
    for (int oi = 0; oi < 32; oi++) {
        const int o = og + oi;
        const float4 cf = coef[o];
        const float gv = g0[o << 12];
        const float xv = x0[o << 12];
        s += cf.w * fmaxf(cf.x * gv + cf.y * xv + cf.z, 0.f);
    }
    atomicAdd(&S[p], s);
}

// ---------------- psi combine: add bias, global stats of s ----------------
__global__ __launch_bounds__(256)
void psi_combine(float* __restrict__ S, const float* __restrict__ pb, float* __restrict__ psum)
{
    const int p = blockIdx.x * 256 + threadIdx.x;
    const float s = pb[0] + S[p];
    S[p] = s;
    float s1 = s, s2 = s * s;
#pragma unroll
    for (int d = 1; d < 64; d <<= 1) {
        s1 += __shfl_xor(s1, d);
        s2 += __shfl_xor(s2, d);
    }
    __shared__ float r1[4], r2[4];
    const int wid = threadIdx.x >> 6, lid = threadIdx.x & 63;
    if (lid == 0) { r1[wid] = s1; r2[wid] = s2; }
    __syncthreads();
    if (threadIdx.x == 0) {
        atomicAdd(&psum[0], r1[0] + r1[1] + r1[2] + r1[3]);
        atomicAdd(&psum[1], r2[0] + r2[1] + r2[2] + r2[3]);
    }
}

__global__ void finalize2(const float* __restrict__ psum, const float* __restrict__ psi_gamma,
                          const float* __restrict__ psi_beta, float* __restrict__ pc)
{
    const float invN = 1.f / (float)Ntot;
    const float m = psum[0] * invN;
    const float v = psum[1] * invN - m * m;
    const float ps = psi_gamma[0] * rsqrtf(v + 1e-5f);
    pc[0] = ps;
    pc[1] = psi_beta[0] - m * ps;
}

// ---------------- out = x * sigmoid(pscale*s + pshift) ----------------
__global__ __launch_bounds__(256)
void final_mul_kernel(const float* __restrict__ x, const float* __restrict__ S,
                      const float* __restrict__ pc, float* __restrict__ out)
{
    const size_t i = ((size_t)blockIdx.x * 256 + threadIdx.x) * 4;
    const int hw = (int)(i & 4095);
    const size_t bc = i >> 12;
    const int b = (int)(bc >> 8);
    const float ps = pc[0], psh = pc[1];
    const float4 xv = *(const float4*)(x + i);
    const float4 sv = *(const float4*)(S + ((size_t)b << 12) + hw);
    float4 r;
    r.x = xv.x * (1.f / (1.f + __expf(-(ps * sv.x + psh))));
    r.y = xv.y * (1.f / (1.f + __expf(-(ps * sv.y + psh))));
    r.z = xv.z * (1.f / (1.f + __expf(-(ps * sv.z + psh))));
    r.w = xv.w * (1.f / (1.f + __expf(-(ps * sv.w + psh))));
    *(float4*)(out + i) = r;
}

extern "C" void kernel_launch(void* const* d_in, const int* in_sizes, int n_in,
                              void* d_out, int out_size, void* d_ws, size_t ws_size,
                              hipStream_t stream)
{
    const float* g         = (const float*)d_in[0];
    const float* x         = (const float*)d_in[1];
    const float* wg_w      = (const float*)d_in[2];
    const float* wg_b      = (const float*)d_in[3];
    const float* wg_gamma  = (const float*)d_in[4];
    const float* wg_beta   = (const float*)d_in[5];
    const float* wx_w      = (const float*)d_in[6];
    const float* wx_b      = (const float*)d_in[7];
    const float* wx_gamma  = (const float*)d_in[8];
    const float* wx_beta   = (const float*)d_in[9];
    const float* psi_w     = (const float*)d_in[10];
    const float* psi_b     = (const float*)d_in[11];
    const float* psi_gamma = (const float*)d_in[12];
    const float* psi_beta  = (const float*)d_in[13];

    float* out = (float*)d_out;
    // d_out doubles as scratch for the two conv outputs (exactly 64 MB),
    // fully overwritten by final_mul_kernel afterwards.
    float* tg = out;
    float* tx = out + (size_t)Bn * Oo * HWn;   // +8388608

    float* ws   = (float*)d_ws;
    float* S    = ws;                 // 65536 floats (accumulated via atomics)
    float* gsum = ws + 65536;         // 128
    float* gsq  = ws + 65664;         // 128
    float* xsum = ws + 65792;         // 128
    float* xsq  = ws + 65920;         // 128
    float* psum = ws + 66048;         // 2 (+2 pad)
    float4* coef = (float4*)(ws + 66052);  // 128 float4 (16B aligned)
    float* pc   = ws + 66564;         // 2

    // zero S + all stat accumulators in one shot
    hipMemsetAsync(ws, 0, 66052 * sizeof(float), stream);

    conv_mfma<<<dim3(HWn / 128, Bn, 2), 256, 0, stream>>>(
        g, x, wg_w, wg_b, wx_w, wx_b, tg, tx, gsum, gsq, xsum, xsq);
    finalize1<<<1, 128, 0, stream>>>(gsum, gsq, xsum, xsq, wg_gamma, wg_beta,
                                     wx_gamma, wx_beta, psi_w, coef);
    psi_partial<<<dim3(Ntot / 256, 4), 256, 0, stream>>>(tg, tx, coef, S);
    psi_combine<<<Ntot / 256, 256, 0, stream>>>(S, psi_b, psum);
    finalize2<<<1, 1, 0, stream>>>(psum, psi_gamma, psi_beta, pc);
    final_mul_kernel<<<(Ntot * Cc) / (4 * 256), 256, 0, stream>>>(x, S, pc, out);
}